// Round 1
// baseline (961.457 us; speedup 1.0000x reference)
//
#include <hip/hip_runtime.h>
#include <math.h>

#define H 256

// ---- workspace layout (float offsets) ----
#define WS_WT_TERM 0u
#define WS_WT_C    196608u
#define WS_WT_A    393216u
#define WS_WT_Q    589824u
#define WS_PT      786432u          // 260*256
#define WS_GI_TERM 852992u          // 20*64*768
#define WS_GI_C    1836032u         // 50*24*768
#define WS_GI_A    2757632u
#define WS_ENC     3679232u         // 64*256
#define WS_HC      3695616u         // 24*256
#define WS_HA      3701760u         // 24*256
#define WS_HCP     3707904u         // 24*256
// total 3714048 floats = ~14.2 MB

__device__ __forceinline__ float sigmoidf_(float x){ return 1.f/(1.f+expf(-x)); }

// ---------------- K0: 64x64 tiled transpose: in[R][C] -> out[C][R] ----------------
__global__ __launch_bounds__(256) void k_transpose(const float* __restrict__ in,
                                                   float* __restrict__ out, int R, int C)
{
    __shared__ float t[64][65];
    const int c0 = blockIdx.x * 64, r0 = blockIdx.y * 64;
    const int cc = threadIdx.x & 63;
    const int rr = threadIdx.x >> 6;   // 0..3
#pragma unroll
    for (int s = 0; s < 16; s++) {
        int row = s * 4 + rr;
        if (r0 + row < R && c0 + cc < C)
            t[row][cc] = in[(size_t)(r0 + row) * C + (c0 + cc)];
    }
    __syncthreads();
#pragma unroll
    for (int s = 0; s < 16; s++) {
        int col = s * 4 + rr;
        if (c0 + col < C && r0 + cc < R)
            out[(size_t)(c0 + col) * R + (r0 + cc)] = t[cc][col];
    }
}

// ---------------- K1: gi GEMM (input-side gate preactivations for all chains/steps) ----
// term: rows = t*64+q (1280 rows), doc_c/doc_a: rows = t*24+d (1200 rows). N=768, K=256.
__global__ __launch_bounds__(256) void k_gi_gemm(
    const int* __restrict__ qtok, const int* __restrict__ ptok, const int* __restrict__ ntok,
    const float* __restrict__ temb, const float* __restrict__ demb,
    const float* __restrict__ tWih, const float* __restrict__ cWih, const float* __restrict__ aWih,
    const float* __restrict__ tbih, const float* __restrict__ cbih, const float* __restrict__ abih,
    float* __restrict__ gi_term, float* __restrict__ gi_c, float* __restrict__ gi_a)
{
    __shared__ __align__(16) float As[64][68];   // As[k][r]
    __shared__ __align__(16) float Bs[64][68];   // Bs[k][j]
    __shared__ int tok[64];
    __shared__ int vld[64];

    const int bid = blockIdx.x, tid = threadIdx.x;
    const float *Wih, *bih, *emb; float* out; int nrows, seg, mt, nt;
    if (bid < 240)      { seg = 0; int b = bid;       mt = b / 12; nt = b % 12; Wih = tWih; bih = tbih; emb = temb; out = gi_term; nrows = 1280; }
    else if (bid < 468) { seg = 1; int b = bid - 240; mt = b / 12; nt = b % 12; Wih = cWih; bih = cbih; emb = demb; out = gi_c;    nrows = 1200; }
    else                { seg = 2; int b = bid - 468; mt = b / 12; nt = b % 12; Wih = aWih; bih = abih; emb = demb; out = gi_a;    nrows = 1200; }

    if (tid < 64) {
        int rg = mt * 64 + tid;
        int v = rg < nrows;
        int token = 0;
        if (v) {
            if (seg == 0) { int t = rg >> 6, q = rg & 63; token = qtok[q * 20 + t]; }
            else          { int t = rg / 24, d = rg % 24; token = (d < 12) ? ptok[d * 50 + t] : ntok[(d - 12) * 50 + t]; }
        }
        tok[tid] = token; vld[tid] = v;
    }
    __syncthreads();

    float acc[4][4];
#pragma unroll
    for (int i = 0; i < 4; i++)
#pragma unroll
        for (int jj = 0; jj < 4; jj++) acc[i][jj] = 0.f;

    const int r0 = (tid >> 4) << 2;       // compute micro-tile rows
    const int j0 = (tid & 15) << 2;       // compute micro-tile cols
    const int jb = nt * 64;
    const int lr = tid & 15;              // load: row/col index base
    const int lk = (tid >> 4) << 2;       // load: k offset

    for (int k0 = 0; k0 < 256; k0 += 64) {
#pragma unroll
        for (int s = 0; s < 4; s++) {
            int r = lr + s * 16;
            float4 v4 = *(const float4*)(emb + (size_t)tok[r] * H + k0 + lk);
            As[lk + 0][r] = v4.x; As[lk + 1][r] = v4.y; As[lk + 2][r] = v4.z; As[lk + 3][r] = v4.w;
            float4 w4 = *(const float4*)(Wih + (size_t)(jb + r) * H + k0 + lk);
            Bs[lk + 0][r] = w4.x; Bs[lk + 1][r] = w4.y; Bs[lk + 2][r] = w4.z; Bs[lk + 3][r] = w4.w;
        }
        __syncthreads();
#pragma unroll 8
        for (int k = 0; k < 64; k++) {
            float4 av = *(const float4*)&As[k][r0];
            float4 bv = *(const float4*)&Bs[k][j0];
            acc[0][0] += av.x * bv.x; acc[0][1] += av.x * bv.y; acc[0][2] += av.x * bv.z; acc[0][3] += av.x * bv.w;
            acc[1][0] += av.y * bv.x; acc[1][1] += av.y * bv.y; acc[1][2] += av.y * bv.z; acc[1][3] += av.y * bv.w;
            acc[2][0] += av.z * bv.x; acc[2][1] += av.z * bv.y; acc[2][2] += av.z * bv.z; acc[2][3] += av.z * bv.w;
            acc[3][0] += av.w * bv.x; acc[3][1] += av.w * bv.y; acc[3][2] += av.w * bv.z; acc[3][3] += av.w * bv.w;
        }
        __syncthreads();
    }

    float4 bias = *(const float4*)(bih + jb + j0);
#pragma unroll
    for (int i = 0; i < 4; i++) {
        int r = r0 + i;
        if (!vld[r]) continue;
        int rg = mt * 64 + r;
        float4 o;
        o.x = acc[i][0] + bias.x; o.y = acc[i][1] + bias.y;
        o.z = acc[i][2] + bias.z; o.w = acc[i][3] + bias.w;
        *(float4*)(out + (size_t)rg * 768 + jb + j0) = o;
    }
}

// ---------------- K2: recurrent scans, one block per chain ----------------
// blocks 0..63: term chains (20 steps). blocks 64..111: doc chains (24 docs x 2 cells, 50 steps).
__global__ __launch_bounds__(768) void k_recurrent(
    const float* __restrict__ WT_term, const float* __restrict__ WT_c, const float* __restrict__ WT_a,
    const float* __restrict__ tbhh, const float* __restrict__ cbhh, const float* __restrict__ abhh,
    const float* __restrict__ gi_term, const float* __restrict__ gi_c, const float* __restrict__ gi_a,
    float* __restrict__ enc, float* __restrict__ hc_raw, float* __restrict__ ha)
{
    __shared__ __align__(16) float hbuf[2][H];
    __shared__ float gh[768];
    const int b = blockIdx.x, j = threadIdx.x;
    const float *WT, *bhh, *gi; float* outp; int T, nch, chain;
    if (b < 64) { WT = WT_term; bhh = tbhh; gi = gi_term; T = 20; nch = 64; chain = b; outp = enc + b * H; }
    else {
        int bb = b - 64; int c = bb / 24, d = bb % 24;
        chain = d; T = 50; nch = 24;
        WT = c ? WT_a : WT_c; bhh = c ? abhh : cbhh; gi = c ? gi_a : gi_c;
        outp = (c ? ha : hc_raw) + d * H;
    }
    const float rb = bhh[j];
    if (j < H) hbuf[0][j] = 0.f;
    __syncthreads();
    int cur = 0;
    for (int t = 0; t < T; t++) {
        const float* __restrict__ grow = gi + (size_t)(t * nch + chain) * 768;
        const float* hc = hbuf[cur];
        float a0 = 0.f, a1 = 0.f, a2 = 0.f, a3 = 0.f;
        const float* wp = WT + j;
        for (int k = 0; k < H; k += 8) {
            float4 h0 = *(const float4*)&hc[k];
            float4 h1 = *(const float4*)&hc[k + 4];
            const float* wk = wp + (size_t)k * 768;
            float w0 = wk[0],    w1 = wk[768],  w2 = wk[1536], w3 = wk[2304];
            float w4 = wk[3072], w5 = wk[3840], w6 = wk[4608], w7 = wk[5376];
            a0 += w0 * h0.x; a1 += w1 * h0.y; a2 += w2 * h0.z; a3 += w3 * h0.w;
            a0 += w4 * h1.x; a1 += w5 * h1.y; a2 += w6 * h1.z; a3 += w7 * h1.w;
        }
        gh[j] = rb + ((a0 + a1) + (a2 + a3));
        __syncthreads();
        if (j < H) {
            float r = sigmoidf_(grow[j]       + gh[j]);
            float z = sigmoidf_(grow[j + 256] + gh[j + 256]);
            float n = tanhf(grow[j + 512] + r * gh[j + 512]);
            hbuf[cur ^ 1][j] = (1.f - z) * n + z * hc[j];
        }
        __syncthreads();
        cur ^= 1;
    }
    if (j < H) outp[j] = hbuf[cur][j];
}

// ---------------- K3: position dense on content vectors ----------------
__global__ __launch_bounds__(256) void k_posd(
    const float* __restrict__ PT, const float* __restrict__ pdb,
    const float* __restrict__ ptab, const float* __restrict__ hc_raw,
    float* __restrict__ hcp)
{
    __shared__ __align__(16) float hl[260];
    const int d = blockIdx.x, j = threadIdx.x;
    if (j < 256) hl[j] = hc_raw[d * H + j];
    if (j < 4)   hl[256 + j] = ptab[(d % 12) * 4 + j];
    __syncthreads();
    float acc = pdb[j];
#pragma unroll 4
    for (int k = 0; k < 260; k++) acc += PT[(size_t)k * 256 + j] * hl[k];
    hcp[d * H + j] = acc;
}

// ---------------- K4: attention + final GRU step (h=0), one block per query ----------------
__global__ __launch_bounds__(256) void k_final(
    const float* __restrict__ enc, const float* __restrict__ ha, const float* __restrict__ hcp,
    const float* __restrict__ WT_q, const float* __restrict__ qbih, const float* __restrict__ qbhh,
    float* __restrict__ out)
{
    __shared__ __align__(16) float ql[H];
    __shared__ float wts[24];
    __shared__ __align__(16) float qs_l[H];
    const int q = blockIdx.x, j = threadIdx.x;
    ql[j] = enc[q * H + j];
    __syncthreads();
    if (j < 192) {
        int dd = j >> 3, l8 = j & 7;
        float s = 0.f;
        for (int k = l8 * 32; k < l8 * 32 + 32; k++) s += ha[dd * H + k] * ql[k];
        s += __shfl_xor(s, 1); s += __shfl_xor(s, 2); s += __shfl_xor(s, 4);
        if (l8 == 0) wts[dd] = s;
    }
    __syncthreads();
    if (j < 2) {
        int base = j * 12;
        float m = wts[base];
        for (int d = 1; d < 12; d++) m = fmaxf(m, wts[base + d]);
        float sum = 0.f;
        for (int d = 0; d < 12; d++) { float e = expf(wts[base + d] - m); wts[base + d] = e; sum += e; }
        float inv = 1.f / sum;
        for (int d = 0; d < 12; d++) wts[base + d] *= inv;
    }
    __syncthreads();
    float qs = ql[j];
#pragma unroll 4
    for (int d = 0; d < 24; d++) qs += wts[d] * hcp[d * H + j];
    qs_l[j] = qs;
    __syncthreads();
    float ar = qbih[j], az = qbih[j + 256], an = qbih[j + 512];
    const float* wp = WT_q + j;
#pragma unroll 4
    for (int k = 0; k < H; k++) {
        float hv = qs_l[k];
        const float* wk = wp + (size_t)k * 768;
        ar += wk[0] * hv; az += wk[256] * hv; an += wk[512] * hv;
    }
    float r = sigmoidf_(ar + qbhh[j]);
    float z = sigmoidf_(az + qbhh[j + 256]);
    float n = tanhf(an + r * qbhh[j + 512]);
    out[q * H + j] = (1.f - z) * n;   // h0 = 0 -> z*h term vanishes
}

extern "C" void kernel_launch(void* const* d_in, const int* in_sizes, int n_in,
                              void* d_out, int out_size, void* d_ws, size_t ws_size,
                              hipStream_t stream)
{
    const int*   qtok = (const int*)d_in[0];
    const int*   ptok = (const int*)d_in[1];
    const int*   ntok = (const int*)d_in[2];
    const float* temb = (const float*)d_in[3];
    const float* tWih = (const float*)d_in[4];
    const float* tWhh = (const float*)d_in[5];
    const float* tbih = (const float*)d_in[6];
    const float* tbhh = (const float*)d_in[7];
    const float* demb = (const float*)d_in[8];
    const float* cWih = (const float*)d_in[9];
    const float* cWhh = (const float*)d_in[10];
    const float* cbih = (const float*)d_in[11];
    const float* cbhh = (const float*)d_in[12];
    const float* aWih = (const float*)d_in[13];
    const float* aWhh = (const float*)d_in[14];
    const float* abih = (const float*)d_in[15];
    const float* abhh = (const float*)d_in[16];
    const float* ptab = (const float*)d_in[17];
    const float* pdW  = (const float*)d_in[18];
    const float* pdb  = (const float*)d_in[19];
    const float* qWih = (const float*)d_in[20];
    const float* qbih = (const float*)d_in[22];
    const float* qbhh = (const float*)d_in[23];

    float* ws  = (float*)d_ws;
    float* WTt = ws + WS_WT_TERM;
    float* WTc = ws + WS_WT_C;
    float* WTa = ws + WS_WT_A;
    float* WTq = ws + WS_WT_Q;
    float* PT  = ws + WS_PT;
    float* GIt = ws + WS_GI_TERM;
    float* GIc = ws + WS_GI_C;
    float* GIa = ws + WS_GI_A;
    float* ENC = ws + WS_ENC;
    float* HC  = ws + WS_HC;
    float* HA  = ws + WS_HA;
    float* HCP = ws + WS_HCP;

    // transposes: Whh/qry_Wih [768][256] -> [256][768]; posd_W [256][260] -> [260][256]
    k_transpose<<<dim3(4, 12), 256, 0, stream>>>(tWhh, WTt, 768, 256);
    k_transpose<<<dim3(4, 12), 256, 0, stream>>>(cWhh, WTc, 768, 256);
    k_transpose<<<dim3(4, 12), 256, 0, stream>>>(aWhh, WTa, 768, 256);
    k_transpose<<<dim3(4, 12), 256, 0, stream>>>(qWih, WTq, 768, 256);
    k_transpose<<<dim3(5, 4),  256, 0, stream>>>(pdW,  PT,  256, 260);

    k_gi_gemm<<<696, 256, 0, stream>>>(qtok, ptok, ntok, temb, demb,
                                       tWih, cWih, aWih, tbih, cbih, abih,
                                       GIt, GIc, GIa);

    k_recurrent<<<112, 768, 0, stream>>>(WTt, WTc, WTa, tbhh, cbhh, abhh,
                                         GIt, GIc, GIa, ENC, HC, HA);

    k_posd<<<24, 256, 0, stream>>>(PT, pdb, ptab, HC, HCP);

    k_final<<<64, 256, 0, stream>>>(ENC, HA, HCP, WTq, qbih, qbhh, (float*)d_out);
}

// Round 2
// 502.798 us; speedup vs baseline: 1.9122x; 1.9122x over previous
//
#include <hip/hip_runtime.h>
#include <hip/hip_fp16.h>
#include <math.h>

#define H 256

typedef _Float16 h2_t __attribute__((ext_vector_type(2)));
union U16x8 { uint4 u; h2_t h[4]; };

// ---- workspace layout (float offsets) ----
#define WS_WTQ   0u           // 196608 f32 (qry_Wih^T, k-major)
#define WS_PT    196608u      // 66560 f32 (posd_W^T)
#define WS_WTPT  263168u      // 98304 f32-equiv = 196608 halves (term Whh packed fp16)
#define WS_WTPC  361472u
#define WS_WTPA  459776u
#define WS_GI_T  558080u      // 20*64*768
#define WS_GI_C  1541120u     // 50*24*768
#define WS_GI_A  2462720u
#define WS_ENC   3384320u     // 64*256
#define WS_HC    3400704u     // 24*256
#define WS_HA    3406848u
#define WS_HCP   3412992u
// end 3419136 floats = 13.7 MB

__device__ __forceinline__ float sigmoidf_(float x){ return 1.f/(1.f+expf(-x)); }

// ---------------- K0a: 64x64 tiled fp32 transpose: in[R][C] -> out[C][R] ----------------
__global__ __launch_bounds__(256) void k_transpose(const float* __restrict__ in,
                                                   float* __restrict__ out, int R, int C)
{
    __shared__ float t[64][65];
    const int c0 = blockIdx.x * 64, r0 = blockIdx.y * 64;
    const int cc = threadIdx.x & 63;
    const int rr = threadIdx.x >> 6;
#pragma unroll
    for (int s = 0; s < 16; s++) {
        int row = s * 4 + rr;
        if (r0 + row < R && c0 + cc < C)
            t[row][cc] = in[(size_t)(r0 + row) * C + (c0 + cc)];
    }
    __syncthreads();
#pragma unroll
    for (int s = 0; s < 16; s++) {
        int col = s * 4 + rr;
        if (c0 + col < C && r0 + cc < R)
            out[(size_t)(c0 + col) * R + (r0 + cc)] = t[cc][col];
    }
}

// ---------------- K0b: pack Whh[768][256] -> fp16 WTp[k/8][768][8] ----------------
// blockIdx.x = row j (0..767), threadIdx.x = k (0..255)
__global__ __launch_bounds__(256) void k_pack16(const float* __restrict__ in,
                                                __half* __restrict__ out)
{
    const int j = blockIdx.x, k = threadIdx.x;
    float v = in[(size_t)j * 256 + k];
    out[(size_t)(k >> 3) * 6144 + j * 8 + (k & 7)] = (__half)v;
}

// ---------------- K1: gi GEMM (input-side gate preactivations) ----------------
__global__ __launch_bounds__(256) void k_gi_gemm(
    const int* __restrict__ qtok, const int* __restrict__ ptok, const int* __restrict__ ntok,
    const float* __restrict__ temb, const float* __restrict__ demb,
    const float* __restrict__ tWih, const float* __restrict__ cWih, const float* __restrict__ aWih,
    const float* __restrict__ tbih, const float* __restrict__ cbih, const float* __restrict__ abih,
    float* __restrict__ gi_term, float* __restrict__ gi_c, float* __restrict__ gi_a)
{
    __shared__ __align__(16) float As[64][68];
    __shared__ __align__(16) float Bs[64][68];
    __shared__ int tok[64];
    __shared__ int vld[64];

    const int bid = blockIdx.x, tid = threadIdx.x;
    const float *Wih, *bih, *emb; float* out; int nrows, seg, mt, nt;
    if (bid < 240)      { seg = 0; int b = bid;       mt = b / 12; nt = b % 12; Wih = tWih; bih = tbih; emb = temb; out = gi_term; nrows = 1280; }
    else if (bid < 468) { seg = 1; int b = bid - 240; mt = b / 12; nt = b % 12; Wih = cWih; bih = cbih; emb = demb; out = gi_c;    nrows = 1200; }
    else                { seg = 2; int b = bid - 468; mt = b / 12; nt = b % 12; Wih = aWih; bih = abih; emb = demb; out = gi_a;    nrows = 1200; }

    if (tid < 64) {
        int rg = mt * 64 + tid;
        int v = rg < nrows;
        int token = 0;
        if (v) {
            if (seg == 0) { int t = rg >> 6, q = rg & 63; token = qtok[q * 20 + t]; }
            else          { int t = rg / 24, d = rg % 24; token = (d < 12) ? ptok[d * 50 + t] : ntok[(d - 12) * 50 + t]; }
        }
        tok[tid] = token; vld[tid] = v;
    }
    __syncthreads();

    float acc[4][4];
#pragma unroll
    for (int i = 0; i < 4; i++)
#pragma unroll
        for (int jj = 0; jj < 4; jj++) acc[i][jj] = 0.f;

    const int r0 = (tid >> 4) << 2;
    const int j0 = (tid & 15) << 2;
    const int jb = nt * 64;
    const int lr = tid & 15;
    const int lk = (tid >> 4) << 2;

    for (int k0 = 0; k0 < 256; k0 += 64) {
#pragma unroll
        for (int s = 0; s < 4; s++) {
            int r = lr + s * 16;
            float4 v4 = *(const float4*)(emb + (size_t)tok[r] * H + k0 + lk);
            As[lk + 0][r] = v4.x; As[lk + 1][r] = v4.y; As[lk + 2][r] = v4.z; As[lk + 3][r] = v4.w;
            float4 w4 = *(const float4*)(Wih + (size_t)(jb + r) * H + k0 + lk);
            Bs[lk + 0][r] = w4.x; Bs[lk + 1][r] = w4.y; Bs[lk + 2][r] = w4.z; Bs[lk + 3][r] = w4.w;
        }
        __syncthreads();
#pragma unroll 8
        for (int k = 0; k < 64; k++) {
            float4 av = *(const float4*)&As[k][r0];
            float4 bv = *(const float4*)&Bs[k][j0];
            acc[0][0] += av.x * bv.x; acc[0][1] += av.x * bv.y; acc[0][2] += av.x * bv.z; acc[0][3] += av.x * bv.w;
            acc[1][0] += av.y * bv.x; acc[1][1] += av.y * bv.y; acc[1][2] += av.y * bv.z; acc[1][3] += av.y * bv.w;
            acc[2][0] += av.z * bv.x; acc[2][1] += av.z * bv.y; acc[2][2] += av.z * bv.z; acc[2][3] += av.z * bv.w;
            acc[3][0] += av.w * bv.x; acc[3][1] += av.w * bv.y; acc[3][2] += av.w * bv.z; acc[3][3] += av.w * bv.w;
        }
        __syncthreads();
    }

    float4 bias = *(const float4*)(bih + jb + j0);
#pragma unroll
    for (int i = 0; i < 4; i++) {
        int r = r0 + i;
        if (!vld[r]) continue;
        int rg = mt * 64 + r;
        float4 o;
        o.x = acc[i][0] + bias.x; o.y = acc[i][1] + bias.y;
        o.z = acc[i][2] + bias.z; o.w = acc[i][3] + bias.w;
        *(float4*)(out + (size_t)rg * 768 + jb + j0) = o;
    }
}

// ---------------- K2: recurrent scans, 4 chains per block, fp16 weights via fdot2 ------
// blocks 0..15: term (chains 4b..4b+3, 20 steps). blocks 16..27: doc (cell=db/6, docs (db%6)*4.., 50 steps)
__global__ __launch_bounds__(768) void k_recur2(
    const __half* __restrict__ WTPt, const __half* __restrict__ WTPc, const __half* __restrict__ WTPa,
    const float* __restrict__ tbhh, const float* __restrict__ cbhh, const float* __restrict__ abhh,
    const float* __restrict__ gi_t, const float* __restrict__ gi_c, const float* __restrict__ gi_a,
    float* __restrict__ enc, float* __restrict__ hc, float* __restrict__ ha)
{
    __shared__ __align__(16) float  hf[2][4][H];   // fp32 state (ping-pong)
    __shared__ __align__(16) __half hh[2][4][H];   // fp16 state for the dot
    __shared__ __align__(16) float  gh[4][768];

    const int b = blockIdx.x, tid = threadIdx.x;
    const __half* WTP; const float *bhh, *gi; float* outp; int T, nch, ch0;
    if (b < 16) { WTP = WTPt; bhh = tbhh; gi = gi_t; T = 20; nch = 64; ch0 = b * 4; outp = enc; }
    else {
        int db = b - 16; int cell = db / 6; int d0 = (db % 6) * 4;
        ch0 = d0; T = 50; nch = 24;
        WTP = cell ? WTPa : WTPc; bhh = cell ? abhh : cbhh; gi = cell ? gi_a : gi_c;
        outp = cell ? ha : hc;
    }
    const float rb = bhh[tid];
    for (int i = tid; i < 4 * H; i += 768) {
        hf[0][i >> 8][i & 255] = 0.f;
        hh[0][i >> 8][i & 255] = (__half)0.f;
    }
    __syncthreads();

    const uint4* __restrict__ W4 = (const uint4*)WTP;
    int cur = 0;
    for (int t = 0; t < T; t++) {
        // ---- matvec: gh[c][tid] = bhh[tid] + sum_k W[tid][k] * h[c][k] ----
        float a0 = 0.f, a1 = 0.f, a2 = 0.f, a3 = 0.f;
        const uint4* h0p = (const uint4*)&hh[cur][0][0];
        const uint4* h1p = (const uint4*)&hh[cur][1][0];
        const uint4* h2p = (const uint4*)&hh[cur][2][0];
        const uint4* h3p = (const uint4*)&hh[cur][3][0];
#pragma unroll 4
        for (int k8 = 0; k8 < 32; k8++) {
            U16x8 wv; wv.u = W4[k8 * 768 + tid];
            U16x8 v0; v0.u = h0p[k8];
            U16x8 v1; v1.u = h1p[k8];
            U16x8 v2; v2.u = h2p[k8];
            U16x8 v3; v3.u = h3p[k8];
#pragma unroll
            for (int p = 0; p < 4; p++) {
                a0 = __builtin_amdgcn_fdot2(wv.h[p], v0.h[p], a0, false);
                a1 = __builtin_amdgcn_fdot2(wv.h[p], v1.h[p], a1, false);
                a2 = __builtin_amdgcn_fdot2(wv.h[p], v2.h[p], a2, false);
                a3 = __builtin_amdgcn_fdot2(wv.h[p], v3.h[p], a3, false);
            }
        }
        gh[0][tid] = rb + a0; gh[1][tid] = rb + a1;
        gh[2][tid] = rb + a2; gh[3][tid] = rb + a3;
        __syncthreads();

        // ---- GRU update: 1024 items = 4 chains x 256 j ----
        {
            int c = tid >> 8, jj = tid & 255;
            const float* grow = gi + (size_t)(t * nch + ch0 + c) * 768;
            float r = sigmoidf_(grow[jj]       + gh[c][jj]);
            float z = sigmoidf_(grow[jj + 256] + gh[c][jj + 256]);
            float n = tanhf(grow[jj + 512] + r * gh[c][jj + 512]);
            float hn = (1.f - z) * n + z * hf[cur][c][jj];
            hf[cur ^ 1][c][jj] = hn;
            hh[cur ^ 1][c][jj] = (__half)hn;
        }
        if (tid < 256) {
            int c = 3, jj = tid;
            const float* grow = gi + (size_t)(t * nch + ch0 + c) * 768;
            float r = sigmoidf_(grow[jj]       + gh[c][jj]);
            float z = sigmoidf_(grow[jj + 256] + gh[c][jj + 256]);
            float n = tanhf(grow[jj + 512] + r * gh[c][jj + 512]);
            float hn = (1.f - z) * n + z * hf[cur][c][jj];
            hf[cur ^ 1][c][jj] = hn;
            hh[cur ^ 1][c][jj] = (__half)hn;
        }
        __syncthreads();
        cur ^= 1;
    }

    if (tid < H) {
#pragma unroll
        for (int c = 0; c < 4; c++)
            outp[(size_t)(ch0 + c) * H + tid] = hf[cur][c][tid];
    }
}

// ---------------- K3: position dense on content vectors ----------------
__global__ __launch_bounds__(256) void k_posd(
    const float* __restrict__ PT, const float* __restrict__ pdb,
    const float* __restrict__ ptab, const float* __restrict__ hc_raw,
    float* __restrict__ hcp)
{
    __shared__ __align__(16) float hl[260];
    const int d = blockIdx.x, j = threadIdx.x;
    if (j < 256) hl[j] = hc_raw[d * H + j];
    if (j < 4)   hl[256 + j] = ptab[(d % 12) * 4 + j];
    __syncthreads();
    float acc = pdb[j];
#pragma unroll 4
    for (int k = 0; k < 260; k++) acc += PT[(size_t)k * 256 + j] * hl[k];
    hcp[d * H + j] = acc;
}

// ---------------- K4: attention + final GRU step (h=0), one block per query ----------------
__global__ __launch_bounds__(256) void k_final(
    const float* __restrict__ enc, const float* __restrict__ ha, const float* __restrict__ hcp,
    const float* __restrict__ WT_q, const float* __restrict__ qbih, const float* __restrict__ qbhh,
    float* __restrict__ out)
{
    __shared__ __align__(16) float ql[H];
    __shared__ float wts[24];
    __shared__ __align__(16) float qs_l[H];
    const int q = blockIdx.x, j = threadIdx.x;
    ql[j] = enc[q * H + j];
    __syncthreads();
    if (j < 192) {
        int dd = j >> 3, l8 = j & 7;
        float s = 0.f;
        for (int k = l8 * 32; k < l8 * 32 + 32; k++) s += ha[dd * H + k] * ql[k];
        s += __shfl_xor(s, 1); s += __shfl_xor(s, 2); s += __shfl_xor(s, 4);
        if (l8 == 0) wts[dd] = s;
    }
    __syncthreads();
    if (j < 2) {
        int base = j * 12;
        float m = wts[base];
        for (int d = 1; d < 12; d++) m = fmaxf(m, wts[base + d]);
        float sum = 0.f;
        for (int d = 0; d < 12; d++) { float e = expf(wts[base + d] - m); wts[base + d] = e; sum += e; }
        float inv = 1.f / sum;
        for (int d = 0; d < 12; d++) wts[base + d] *= inv;
    }
    __syncthreads();
    float qs = ql[j];
#pragma unroll 4
    for (int d = 0; d < 24; d++) qs += wts[d] * hcp[d * H + j];
    qs_l[j] = qs;
    __syncthreads();
    float ar = qbih[j], az = qbih[j + 256], an = qbih[j + 512];
    const float* wp = WT_q + j;
#pragma unroll 4
    for (int k = 0; k < H; k++) {
        float hv = qs_l[k];
        const float* wk = wp + (size_t)k * 768;
        ar += wk[0] * hv; az += wk[256] * hv; an += wk[512] * hv;
    }
    float r = sigmoidf_(ar + qbhh[j]);
    float z = sigmoidf_(az + qbhh[j + 256]);
    float n = tanhf(an + r * qbhh[j + 512]);
    out[q * H + j] = (1.f - z) * n;   // h0 = 0 -> z*h term vanishes
}

extern "C" void kernel_launch(void* const* d_in, const int* in_sizes, int n_in,
                              void* d_out, int out_size, void* d_ws, size_t ws_size,
                              hipStream_t stream)
{
    const int*   qtok = (const int*)d_in[0];
    const int*   ptok = (const int*)d_in[1];
    const int*   ntok = (const int*)d_in[2];
    const float* temb = (const float*)d_in[3];
    const float* tWih = (const float*)d_in[4];
    const float* tWhh = (const float*)d_in[5];
    const float* tbih = (const float*)d_in[6];
    const float* tbhh = (const float*)d_in[7];
    const float* demb = (const float*)d_in[8];
    const float* cWih = (const float*)d_in[9];
    const float* cWhh = (const float*)d_in[10];
    const float* cbih = (const float*)d_in[11];
    const float* cbhh = (const float*)d_in[12];
    const float* aWih = (const float*)d_in[13];
    const float* aWhh = (const float*)d_in[14];
    const float* abih = (const float*)d_in[15];
    const float* abhh = (const float*)d_in[16];
    const float* ptab = (const float*)d_in[17];
    const float* pdW  = (const float*)d_in[18];
    const float* pdb  = (const float*)d_in[19];
    const float* qWih = (const float*)d_in[20];
    const float* qbih = (const float*)d_in[22];
    const float* qbhh = (const float*)d_in[23];

    float* ws  = (float*)d_ws;
    float*  WTq  = ws + WS_WTQ;
    float*  PT   = ws + WS_PT;
    __half* WTPt = (__half*)(ws + WS_WTPT);
    __half* WTPc = (__half*)(ws + WS_WTPC);
    __half* WTPa = (__half*)(ws + WS_WTPA);
    float* GIt = ws + WS_GI_T;
    float* GIc = ws + WS_GI_C;
    float* GIa = ws + WS_GI_A;
    float* ENC = ws + WS_ENC;
    float* HC  = ws + WS_HC;
    float* HA  = ws + WS_HA;
    float* HCP = ws + WS_HCP;

    // weight prep
    k_transpose<<<dim3(4, 12), 256, 0, stream>>>(qWih, WTq, 768, 256);
    k_transpose<<<dim3(5, 4),  256, 0, stream>>>(pdW,  PT,  256, 260);
    k_pack16<<<768, 256, 0, stream>>>(tWhh, WTPt);
    k_pack16<<<768, 256, 0, stream>>>(cWhh, WTPc);
    k_pack16<<<768, 256, 0, stream>>>(aWhh, WTPa);

    k_gi_gemm<<<696, 256, 0, stream>>>(qtok, ptok, ntok, temb, demb,
                                       tWih, cWih, aWih, tbih, cbih, abih,
                                       GIt, GIc, GIa);

    k_recur2<<<28, 768, 0, stream>>>(WTPt, WTPc, WTPa, tbhh, cbhh, abhh,
                                     GIt, GIc, GIa, ENC, HC, HA);

    k_posd<<<24, 256, 0, stream>>>(PT, pdb, ptab, HC, HCP);

    k_final<<<64, 256, 0, stream>>>(ENC, HA, HCP, WTq, qbih, qbhh, (float*)d_out);
}